// Round 1
// baseline (1762.973 us; speedup 1.0000x reference)
//
#include <hip/hip_runtime.h>

#define DIMS 128
#define RPB 64           // rows per bucket
#define CAP 3072         // edge capacity per bucket (avg 2047, ~23 sigma margin)
#define NBINS 1024       // per bucket: 64 rows x 16 column bands (band = col>>13 in [0,12])

typedef _Float16 half_t;
typedef _Float16 half2_t __attribute__((ext_vector_type(2)));

static __device__ __forceinline__ unsigned halfbits(float v) {
    half_t h = (half_t)v;
    unsigned short us;
    __builtin_memcpy(&us, &h, 2);
    return (unsigned)us;
}
static __device__ __forceinline__ half2_t h2(int b) { return __builtin_bit_cast(half2_t, b); }
static __device__ __forceinline__ int ih(half2_t h) { return __builtin_bit_cast(int, h); }

// fp32 -> fp16 convert (x -> xh), 2 elems/thread
__global__ void cvt_kernel(const float* __restrict__ src, half_t* __restrict__ dst, int n2) {
    int i = blockIdx.x * blockDim.x + threadIdx.x;
    if (i >= n2) return;
    float2 v = reinterpret_cast<const float2*>(src)[i];
    half2_t h;
    h.x = (half_t)v.x;
    h.y = (half_t)v.y;
    reinterpret_cast<half2_t*>(&dst[0])[i] = h;
}

// Pass A: per-bin histogram. bin = r*16 + (c>>13), which IS bucket-major layout
// ((r>>6)*1024 + (r&63)*16 + band) because 64 rows * 16 bands = 1024.
__global__ __launch_bounds__(256) void hist_kernel(
    const int* __restrict__ row, const int* __restrict__ col, int E,
    int* __restrict__ hist) {
    int e = (blockIdx.x * 256 + threadIdx.x) * 4;
    if (e + 3 < E) {
        int4 r4 = *reinterpret_cast<const int4*>(&row[e]);
        int4 c4 = *reinterpret_cast<const int4*>(&col[e]);
        atomicAdd(&hist[(r4.x << 4) + (c4.x >> 13)], 1);
        atomicAdd(&hist[(r4.y << 4) + (c4.y >> 13)], 1);
        atomicAdd(&hist[(r4.z << 4) + (c4.z >> 13)], 1);
        atomicAdd(&hist[(r4.w << 4) + (c4.w >> 13)], 1);
    } else {
        for (int j = e; j < E; ++j)
            atomicAdd(&hist[(row[j] << 4) + (col[j] >> 13)], 1);
    }
}

// Pass B: per-bucket exclusive scan of 1024 bins, in-place (counts -> start
// positions relative to bucket base). Also emits per-row (start<<16 | end).
__global__ __launch_bounds__(256) void scan_kernel(
    int* __restrict__ hist, int* __restrict__ rowinfo, int N) {
    __shared__ int pos[NBINS + 1];
    __shared__ int wsum[4];
    const int b = blockIdx.x;
    const int t = threadIdx.x;
    const int lane = t & 63, w = t >> 6;
    int* hb = hist + (size_t)b * NBINS;
    int4 h = *reinterpret_cast<const int4*>(&hb[4 * t]);
    const int s = h.x + h.y + h.z + h.w;
    int v = s;
#pragma unroll
    for (int d = 1; d < 64; d <<= 1) {
        int u = __shfl_up(v, d, 64);
        if (lane >= d) v += u;
    }
    if (lane == 63) wsum[w] = v;
    __syncthreads();
    int wbase = 0;
    if (w > 0) wbase += wsum[0];
    if (w > 1) wbase += wsum[1];
    if (w > 2) wbase += wsum[2];
    const int e0 = wbase + v - s;
    const int e1 = e0 + h.x, e2 = e1 + h.y, e3 = e2 + h.z;
    pos[4 * t] = e0;
    pos[4 * t + 1] = e1;
    pos[4 * t + 2] = e2;
    pos[4 * t + 3] = e3;
    if (t == 255) pos[NBINS] = e3 + h.w;
    *reinterpret_cast<int4*>(&hb[4 * t]) = make_int4(e0, e1, e2, e3);
    __syncthreads();
    if (t < RPB) {
        const int rstart = min(pos[t * 16], CAP);
        const int rend = min(pos[t * 16 + 16], CAP);
        const int rr = b * RPB + t;
        if (rr < N) rowinfo[rr] = (rstart << 16) | rend;
    }
}

// Pass C: scatter edges directly to their final sorted slot. hist[bin] is the
// running cursor (starts at bin's exclusive-scan position within its bucket).
// pk.x = col<<8 (byte offset into fp16 table); pk.y = half2{v,v}.
__global__ __launch_bounds__(256) void scatter_kernel(
    const int* __restrict__ row, const int* __restrict__ col,
    const float* __restrict__ val, int E,
    int* __restrict__ hist, int2* __restrict__ staged) {
    int e = (blockIdx.x * 256 + threadIdx.x) * 4;
    if (e + 3 < E) {
        int4 r4 = *reinterpret_cast<const int4*>(&row[e]);
        int4 c4 = *reinterpret_cast<const int4*>(&col[e]);
        float4 v4 = *reinterpret_cast<const float4*>(&val[e]);
        int rr[4] = {r4.x, r4.y, r4.z, r4.w};
        int cc[4] = {c4.x, c4.y, c4.z, c4.w};
        float vv[4] = {v4.x, v4.y, v4.z, v4.w};
#pragma unroll
        for (int j = 0; j < 4; ++j) {
            int p = atomicAdd(&hist[(rr[j] << 4) + (cc[j] >> 13)], 1);
            if (p < CAP) {
                unsigned hb = halfbits(vv[j]);
                int2 pk;
                pk.x = (int)((unsigned)cc[j] << 8);
                pk.y = (int)((hb << 16) | hb);
                staged[(size_t)(rr[j] >> 6) * CAP + p] = pk;
            }
        }
    } else {
        for (int j = e; j < E; ++j) {
            int r = row[j], c = col[j];
            int p = atomicAdd(&hist[(r << 4) + (c >> 13)], 1);
            if (p < CAP) {
                unsigned hb = halfbits(val[j]);
                int2 pk;
                pk.x = (int)((unsigned)c << 8);
                pk.y = (int)((hb << 16) | hb);
                staged[(size_t)(r >> 6) * CAP + p] = pk;
            }
        }
    }
}

// ---------------- SpMM: one wave per row, 16-lane edge groups ----------------
// Edge list loaded ONCE per row, coalesced (lane i holds edge start+i), then
// broadcast per 4-edge group via one __shfl pair. Each 16-lane group owns one
// edge per step; each lane gathers 16B (8 dims) with global_load_dwordx4 ->
// 8 cache lines in flight per gather instruction (vs 2 with dword), and
// ~2.5x fewer issue slots per edge. Cross-group 4-way butterfly at the end.
// MODE 0: emb_out = A*xh;   acc_h = xh + A*xh        (layer 1)
// MODE 1: emb_out = A*e1;   acc_h += A*e1            (layer 2, emb_out==xh reused)
// MODE 2: out = (acc_h + A*e2) * 0.25  (fp32 final)  (layer 3)
template <int MODE>
__global__ __launch_bounds__(256) void spmm_kernel(
    const half_t* __restrict__ emb_in, const int* __restrict__ rowinfo,
    const int2* __restrict__ staged, int N,
    half_t* __restrict__ emb_out, half_t* __restrict__ acc_h,
    float* __restrict__ out) {
    const int r = (blockIdx.x * blockDim.x + threadIdx.x) >> 6;  // wave id = row
    const int lane = threadIdx.x & 63;
    if (r >= N) return;
    const int info = rowinfo[r];
    const int start = info >> 16;
    const int end = info & 0xFFFF;
    const int2* eb = staged + (size_t)(r >> 6) * CAP;
    const char* tbl = reinterpret_cast<const char*>(emb_in);
    const int g = lane >> 4;                          // edge group 0..3
    const unsigned q16 = (unsigned)(lane & 15) << 4;  // byte offset of this lane's 8 dims

    half2_t acc[4][4];
#pragma unroll
    for (int u = 0; u < 4; ++u)
#pragma unroll
        for (int s = 0; s < 4; ++s) acc[u][s] = (half2_t)0;

    for (int base = start; base < end; base += 64) {
        const int cnt = min(64, end - base);
        int2 myE = make_int2(0, 0);
        if (base + lane < end) myE = eb[base + lane];

        int k = 0;
        for (; k + 16 <= cnt; k += 16) {
            int ex[4], ey[4];
#pragma unroll
            for (int u = 0; u < 4; ++u) {
                ex[u] = __shfl(myE.x, k + 4 * u + g, 64);
                ey[u] = __shfl(myE.y, k + 4 * u + g, 64);
            }
            int4 tv[4];
#pragma unroll
            for (int u = 0; u < 4; ++u) {
                unsigned voff = ((unsigned)ex[u] & 0x03FFFF00u) + q16;
                tv[u] = *reinterpret_cast<const int4*>(tbl + voff);
            }
#pragma unroll
            for (int u = 0; u < 4; ++u) {
                half2_t vv = h2(ey[u]);
                acc[u][0] = h2(tv[u].x) * vv + acc[u][0];
                acc[u][1] = h2(tv[u].y) * vv + acc[u][1];
                acc[u][2] = h2(tv[u].z) * vv + acc[u][2];
                acc[u][3] = h2(tv[u].w) * vv + acc[u][3];
            }
        }
        // tail: groups past cnt read a clamped (valid) edge but with val = 0
        for (; k < cnt; k += 4) {
            const int idx = k + g;
            const int cl = min(idx, cnt - 1);
            int ex = __shfl(myE.x, cl, 64);
            int ey = __shfl(myE.y, cl, 64);
            if (idx >= cnt) ey = 0;
            unsigned voff = ((unsigned)ex & 0x03FFFF00u) + q16;
            int4 t4 = *reinterpret_cast<const int4*>(tbl + voff);
            half2_t vv = h2(ey);
            const int u = (k >> 2) & 3;
            acc[u][0] = h2(t4.x) * vv + acc[u][0];
            acc[u][1] = h2(t4.y) * vv + acc[u][1];
            acc[u][2] = h2(t4.z) * vv + acc[u][2];
            acc[u][3] = h2(t4.w) * vv + acc[u][3];
        }
    }

    half2_t a0 = (acc[0][0] + acc[1][0]) + (acc[2][0] + acc[3][0]);
    half2_t a1 = (acc[0][1] + acc[1][1]) + (acc[2][1] + acc[3][1]);
    half2_t a2 = (acc[0][2] + acc[1][2]) + (acc[2][2] + acc[3][2]);
    half2_t a3 = (acc[0][3] + acc[1][3]) + (acc[2][3] + acc[3][3]);
    // combine the 4 edge groups: lanes q, q+16, q+32, q+48 hold the same dims
#pragma unroll
    for (int off = 16; off < 64; off <<= 1) {
        a0 = a0 + h2(__shfl_xor(ih(a0), off, 64));
        a1 = a1 + h2(__shfl_xor(ih(a1), off, 64));
        a2 = a2 + h2(__shfl_xor(ih(a2), off, 64));
        a3 = a3 + h2(__shfl_xor(ih(a3), off, 64));
    }

    if (lane < 16) {
        const size_t o = (size_t)r * DIMS + ((size_t)lane << 3);  // 8 halves / lane
        if (MODE == 0 || MODE == 1) {
            *reinterpret_cast<int4*>(&emb_out[o]) = make_int4(ih(a0), ih(a1), ih(a2), ih(a3));
        }
        if (MODE == 0) {
            int4 xv = *reinterpret_cast<const int4*>(&emb_in[o]);
            *reinterpret_cast<int4*>(&acc_h[o]) = make_int4(
                ih(h2(xv.x) + a0), ih(h2(xv.y) + a1), ih(h2(xv.z) + a2), ih(h2(xv.w) + a3));
        } else if (MODE == 1) {
            int4 cv = *reinterpret_cast<const int4*>(&acc_h[o]);
            *reinterpret_cast<int4*>(&acc_h[o]) = make_int4(
                ih(h2(cv.x) + a0), ih(h2(cv.y) + a1), ih(h2(cv.z) + a2), ih(h2(cv.w) + a3));
        } else {
            int4 cv = *reinterpret_cast<const int4*>(&acc_h[o]);
            half2_t c0 = h2(cv.x), c1 = h2(cv.y), c2 = h2(cv.z), c3 = h2(cv.w);
            float4 f0 = make_float4(((float)c0.x + (float)a0.x) * 0.25f,
                                    ((float)c0.y + (float)a0.y) * 0.25f,
                                    ((float)c1.x + (float)a1.x) * 0.25f,
                                    ((float)c1.y + (float)a1.y) * 0.25f);
            float4 f1 = make_float4(((float)c2.x + (float)a2.x) * 0.25f,
                                    ((float)c2.y + (float)a2.y) * 0.25f,
                                    ((float)c3.x + (float)a3.x) * 0.25f,
                                    ((float)c3.y + (float)a3.y) * 0.25f);
            float4* po = reinterpret_cast<float4*>(&out[o]);
            po[0] = f0;
            po[1] = f1;
        }
    }
}

// ---------------- launch ----------------

extern "C" void kernel_launch(void* const* d_in, const int* in_sizes, int n_in,
                              void* d_out, int out_size, void* d_ws, size_t ws_size,
                              hipStream_t stream) {
    const float* x = (const float*)d_in[0];
    const int* erow = (const int*)d_in[1];
    const int* ecol = (const int*)d_in[2];
    const float* eval = (const float*)d_in[3];
    const int N = in_sizes[0] / DIMS;  // 100000
    const int E = in_sizes[1];         // 3200000
    float* out = (float*)d_out;
    const int nbk = (N + RPB - 1) / RPB;  // 1563

    char* ws = (char*)d_ws;
    size_t off = 0;
    auto carve = [&](size_t bytes) {
        void* p = ws + off;
        off = (off + bytes + 255) & ~(size_t)255;
        return p;
    };
    half_t* xh = (half_t*)carve((size_t)N * DIMS * sizeof(half_t));  // also layer-2 output
    half_t* embB1 = (half_t*)carve((size_t)N * DIMS * sizeof(half_t));
    half_t* acc_h = (half_t*)carve((size_t)N * DIMS * sizeof(half_t));
    int2* staged = (int2*)carve((size_t)nbk * CAP * sizeof(int2));
    int* rowinfo = (int*)carve((size_t)N * sizeof(int));
    // hist (6.4 MB) aliases embB1 (25.6 MB): hist is dead before spmm<0> writes embB1
    int* hist = (int*)embB1;
    (void)ws_size;

    hipMemsetAsync(hist, 0, (size_t)nbk * NBINS * sizeof(int), stream);
    const int n2 = N * DIMS / 2;
    cvt_kernel<<<(n2 + 255) / 256, 256, 0, stream>>>(x, xh, n2);
    const int eblocks = (E + 1023) / 1024;
    hist_kernel<<<eblocks, 256, 0, stream>>>(erow, ecol, E, hist);
    scan_kernel<<<nbk, 256, 0, stream>>>(hist, rowinfo, N);
    scatter_kernel<<<eblocks, 256, 0, stream>>>(erow, ecol, eval, E, hist, staged);

    const int spmm_blocks = (N + 3) / 4;  // 4 waves (rows) per 256-thread block
    spmm_kernel<0><<<spmm_blocks, 256, 0, stream>>>(xh, rowinfo, staged, N, embB1, acc_h, out);
    spmm_kernel<1><<<spmm_blocks, 256, 0, stream>>>(embB1, rowinfo, staged, N, xh, acc_h, out);
    spmm_kernel<2><<<spmm_blocks, 256, 0, stream>>>(xh, rowinfo, staged, N, embB1, acc_h, out);
}

// Round 2
// 825.727 us; speedup vs baseline: 2.1351x; 2.1351x over previous
//
#include <hip/hip_runtime.h>

#define DIMS 128
#define RPB 64           // rows per bucket
#define CAP 3072         // edge capacity per bucket (avg 2047, ~23 sigma margin)
#define NBINS 1024       // per bucket: 64 rows x 16 column bands (band = col>>13 in [0,12])

typedef _Float16 half_t;
typedef _Float16 half2_t __attribute__((ext_vector_type(2)));

static __device__ __forceinline__ unsigned halfbits(float v) {
    half_t h = (half_t)v;
    unsigned short us;
    __builtin_memcpy(&us, &h, 2);
    return (unsigned)us;
}
static __device__ __forceinline__ half2_t h2(int b) { return __builtin_bit_cast(half2_t, b); }
static __device__ __forceinline__ int ih(half2_t h) { return __builtin_bit_cast(int, h); }

// fp32 -> fp16 convert (x -> xh), 2 elems/thread
__global__ void cvt_kernel(const float* __restrict__ src, half_t* __restrict__ dst, int n2) {
    int i = blockIdx.x * blockDim.x + threadIdx.x;
    if (i >= n2) return;
    float2 v = reinterpret_cast<const float2*>(src)[i];
    half2_t h;
    h.x = (half_t)v.x;
    h.y = (half_t)v.y;
    reinterpret_cast<half2_t*>(&dst[0])[i] = h;
}

// Pass A: per-bin histogram. bin = r*16 + (c>>13), which IS bucket-major layout
// ((r>>6)*1024 + (r&63)*16 + band) because 64 rows * 16 bands = 1024.
__global__ __launch_bounds__(256) void hist_kernel(
    const int* __restrict__ row, const int* __restrict__ col, int E,
    int* __restrict__ hist) {
    int e = (blockIdx.x * 256 + threadIdx.x) * 4;
    if (e + 3 < E) {
        int4 r4 = *reinterpret_cast<const int4*>(&row[e]);
        int4 c4 = *reinterpret_cast<const int4*>(&col[e]);
        atomicAdd(&hist[(r4.x << 4) + (c4.x >> 13)], 1);
        atomicAdd(&hist[(r4.y << 4) + (c4.y >> 13)], 1);
        atomicAdd(&hist[(r4.z << 4) + (c4.z >> 13)], 1);
        atomicAdd(&hist[(r4.w << 4) + (c4.w >> 13)], 1);
    } else {
        for (int j = e; j < E; ++j)
            atomicAdd(&hist[(row[j] << 4) + (col[j] >> 13)], 1);
    }
}

// Pass B: per-bucket exclusive scan of 1024 bins, in-place (counts -> start
// positions relative to bucket base). Also emits per-row (start<<16 | end).
__global__ __launch_bounds__(256) void scan_kernel(
    int* __restrict__ hist, int* __restrict__ rowinfo, int N) {
    __shared__ int pos[NBINS + 1];
    __shared__ int wsum[4];
    const int b = blockIdx.x;
    const int t = threadIdx.x;
    const int lane = t & 63, w = t >> 6;
    int* hb = hist + (size_t)b * NBINS;
    int4 h = *reinterpret_cast<const int4*>(&hb[4 * t]);
    const int s = h.x + h.y + h.z + h.w;
    int v = s;
#pragma unroll
    for (int d = 1; d < 64; d <<= 1) {
        int u = __shfl_up(v, d, 64);
        if (lane >= d) v += u;
    }
    if (lane == 63) wsum[w] = v;
    __syncthreads();
    int wbase = 0;
    if (w > 0) wbase += wsum[0];
    if (w > 1) wbase += wsum[1];
    if (w > 2) wbase += wsum[2];
    const int e0 = wbase + v - s;
    const int e1 = e0 + h.x, e2 = e1 + h.y, e3 = e2 + h.z;
    pos[4 * t] = e0;
    pos[4 * t + 1] = e1;
    pos[4 * t + 2] = e2;
    pos[4 * t + 3] = e3;
    if (t == 255) pos[NBINS] = e3 + h.w;
    *reinterpret_cast<int4*>(&hb[4 * t]) = make_int4(e0, e1, e2, e3);
    __syncthreads();
    if (t < RPB) {
        const int rstart = min(pos[t * 16], CAP);
        const int rend = min(pos[t * 16 + 16], CAP);
        const int rr = b * RPB + t;
        if (rr < N) rowinfo[rr] = (rstart << 16) | rend;
    }
}

// Pass C: scatter edges directly to their final sorted slot. hist[bin] is the
// running cursor (starts at bin's exclusive-scan position within its bucket).
// pk.x = col<<8 (byte offset into fp16 table); pk.y = half2{v,v}.
__global__ __launch_bounds__(256) void scatter_kernel(
    const int* __restrict__ row, const int* __restrict__ col,
    const float* __restrict__ val, int E,
    int* __restrict__ hist, int2* __restrict__ staged) {
    int e = (blockIdx.x * 256 + threadIdx.x) * 4;
    if (e + 3 < E) {
        int4 r4 = *reinterpret_cast<const int4*>(&row[e]);
        int4 c4 = *reinterpret_cast<const int4*>(&col[e]);
        float4 v4 = *reinterpret_cast<const float4*>(&val[e]);
        int rr[4] = {r4.x, r4.y, r4.z, r4.w};
        int cc[4] = {c4.x, c4.y, c4.z, c4.w};
        float vv[4] = {v4.x, v4.y, v4.z, v4.w};
#pragma unroll
        for (int j = 0; j < 4; ++j) {
            int p = atomicAdd(&hist[(rr[j] << 4) + (cc[j] >> 13)], 1);
            if (p < CAP) {
                unsigned hb = halfbits(vv[j]);
                int2 pk;
                pk.x = (int)((unsigned)cc[j] << 8);
                pk.y = (int)((hb << 16) | hb);
                staged[(size_t)(rr[j] >> 6) * CAP + p] = pk;
            }
        }
    } else {
        for (int j = e; j < E; ++j) {
            int r = row[j], c = col[j];
            int p = atomicAdd(&hist[(r << 4) + (c >> 13)], 1);
            if (p < CAP) {
                unsigned hb = halfbits(val[j]);
                int2 pk;
                pk.x = (int)((unsigned)c << 8);
                pk.y = (int)((hb << 16) | hb);
                staged[(size_t)(r >> 6) * CAP + p] = pk;
            }
        }
    }
}

// ---------------- SpMM: one wave per row, 16-lane edge groups ----------------
// Edge list loaded ONCE per row, coalesced (lane i holds edge start+i), then
// broadcast per 4-edge group via one __shfl pair. Each 16-lane group owns one
// edge per step; each lane gathers 16B (8 dims) with global_load_dwordx4 ->
// 8 cache lines in flight per gather instruction (vs 2 with dword), and
// ~2.5x fewer issue slots per edge. Cross-group 4-way butterfly at the end.
// NOTE (rule #20): every access to acc[][] must be a compile-time index --
// the tail is ONE masked 16-edge iteration, never a runtime-indexed loop.
// MODE 0: emb_out = A*xh;   acc_h = xh + A*xh        (layer 1)
// MODE 1: emb_out = A*e1;   acc_h += A*e1            (layer 2, emb_out==xh reused)
// MODE 2: out = (acc_h + A*e2) * 0.25  (fp32 final)  (layer 3)
template <int MODE>
__global__ __launch_bounds__(256) void spmm_kernel(
    const half_t* __restrict__ emb_in, const int* __restrict__ rowinfo,
    const int2* __restrict__ staged, int N,
    half_t* __restrict__ emb_out, half_t* __restrict__ acc_h,
    float* __restrict__ out) {
    const int r = (blockIdx.x * blockDim.x + threadIdx.x) >> 6;  // wave id = row
    const int lane = threadIdx.x & 63;
    if (r >= N) return;
    const int info = rowinfo[r];
    const int start = info >> 16;
    const int end = info & 0xFFFF;
    const int2* eb = staged + (size_t)(r >> 6) * CAP;
    const char* tbl = reinterpret_cast<const char*>(emb_in);
    const int g = lane >> 4;                          // edge group 0..3
    const unsigned q16 = (unsigned)(lane & 15) << 4;  // byte offset of this lane's 8 dims

    half2_t acc[4][4];
#pragma unroll
    for (int u = 0; u < 4; ++u)
#pragma unroll
        for (int s = 0; s < 4; ++s) acc[u][s] = (half2_t)0;

    for (int base = start; base < end; base += 64) {
        const int cnt = min(64, end - base);
        int2 myE = make_int2(0, 0);
        if (base + lane < end) myE = eb[base + lane];

        int k = 0;
        for (; k + 16 <= cnt; k += 16) {
            int ex[4], ey[4];
#pragma unroll
            for (int u = 0; u < 4; ++u) {
                ex[u] = __shfl(myE.x, k + 4 * u + g, 64);
                ey[u] = __shfl(myE.y, k + 4 * u + g, 64);
            }
            int4 tv[4];
#pragma unroll
            for (int u = 0; u < 4; ++u) {
                unsigned voff = ((unsigned)ex[u] & 0x03FFFF00u) + q16;
                tv[u] = *reinterpret_cast<const int4*>(tbl + voff);
            }
#pragma unroll
            for (int u = 0; u < 4; ++u) {
                half2_t vv = h2(ey[u]);
                acc[u][0] = h2(tv[u].x) * vv + acc[u][0];
                acc[u][1] = h2(tv[u].y) * vv + acc[u][1];
                acc[u][2] = h2(tv[u].z) * vv + acc[u][2];
                acc[u][3] = h2(tv[u].w) * vv + acc[u][3];
            }
        }
        // tail (< 16 edges): one masked iteration, statically indexed.
        // Groups past cnt read a clamped (valid) edge but with val = 0.
        if (k < cnt) {
            int ex[4], ey[4];
#pragma unroll
            for (int u = 0; u < 4; ++u) {
                const int idx = k + 4 * u + g;
                const int cl = min(idx, cnt - 1);
                ex[u] = __shfl(myE.x, cl, 64);
                int t = __shfl(myE.y, cl, 64);
                ey[u] = (idx < cnt) ? t : 0;
            }
            int4 tv[4];
#pragma unroll
            for (int u = 0; u < 4; ++u) {
                unsigned voff = ((unsigned)ex[u] & 0x03FFFF00u) + q16;
                tv[u] = *reinterpret_cast<const int4*>(tbl + voff);
            }
#pragma unroll
            for (int u = 0; u < 4; ++u) {
                half2_t vv = h2(ey[u]);
                acc[u][0] = h2(tv[u].x) * vv + acc[u][0];
                acc[u][1] = h2(tv[u].y) * vv + acc[u][1];
                acc[u][2] = h2(tv[u].z) * vv + acc[u][2];
                acc[u][3] = h2(tv[u].w) * vv + acc[u][3];
            }
        }
    }

    half2_t a0 = (acc[0][0] + acc[1][0]) + (acc[2][0] + acc[3][0]);
    half2_t a1 = (acc[0][1] + acc[1][1]) + (acc[2][1] + acc[3][1]);
    half2_t a2 = (acc[0][2] + acc[1][2]) + (acc[2][2] + acc[3][2]);
    half2_t a3 = (acc[0][3] + acc[1][3]) + (acc[2][3] + acc[3][3]);
    // combine the 4 edge groups: lanes q, q+16, q+32, q+48 hold the same dims
#pragma unroll
    for (int off = 16; off < 64; off <<= 1) {
        a0 = a0 + h2(__shfl_xor(ih(a0), off, 64));
        a1 = a1 + h2(__shfl_xor(ih(a1), off, 64));
        a2 = a2 + h2(__shfl_xor(ih(a2), off, 64));
        a3 = a3 + h2(__shfl_xor(ih(a3), off, 64));
    }

    if (lane < 16) {
        const size_t o = (size_t)r * DIMS + ((size_t)lane << 3);  // 8 halves / lane
        if (MODE == 0 || MODE == 1) {
            *reinterpret_cast<int4*>(&emb_out[o]) = make_int4(ih(a0), ih(a1), ih(a2), ih(a3));
        }
        if (MODE == 0) {
            int4 xv = *reinterpret_cast<const int4*>(&emb_in[o]);
            *reinterpret_cast<int4*>(&acc_h[o]) = make_int4(
                ih(h2(xv.x) + a0), ih(h2(xv.y) + a1), ih(h2(xv.z) + a2), ih(h2(xv.w) + a3));
        } else if (MODE == 1) {
            int4 cv = *reinterpret_cast<const int4*>(&acc_h[o]);
            *reinterpret_cast<int4*>(&acc_h[o]) = make_int4(
                ih(h2(cv.x) + a0), ih(h2(cv.y) + a1), ih(h2(cv.z) + a2), ih(h2(cv.w) + a3));
        } else {
            int4 cv = *reinterpret_cast<const int4*>(&acc_h[o]);
            half2_t c0 = h2(cv.x), c1 = h2(cv.y), c2 = h2(cv.z), c3 = h2(cv.w);
            float4 f0 = make_float4(((float)c0.x + (float)a0.x) * 0.25f,
                                    ((float)c0.y + (float)a0.y) * 0.25f,
                                    ((float)c1.x + (float)a1.x) * 0.25f,
                                    ((float)c1.y + (float)a1.y) * 0.25f);
            float4 f1 = make_float4(((float)c2.x + (float)a2.x) * 0.25f,
                                    ((float)c2.y + (float)a2.y) * 0.25f,
                                    ((float)c3.x + (float)a3.x) * 0.25f,
                                    ((float)c3.y + (float)a3.y) * 0.25f);
            float4* po = reinterpret_cast<float4*>(&out[o]);
            po[0] = f0;
            po[1] = f1;
        }
    }
}

// ---------------- launch ----------------

extern "C" void kernel_launch(void* const* d_in, const int* in_sizes, int n_in,
                              void* d_out, int out_size, void* d_ws, size_t ws_size,
                              hipStream_t stream) {
    const float* x = (const float*)d_in[0];
    const int* erow = (const int*)d_in[1];
    const int* ecol = (const int*)d_in[2];
    const float* eval = (const float*)d_in[3];
    const int N = in_sizes[0] / DIMS;  // 100000
    const int E = in_sizes[1];         // 3200000
    float* out = (float*)d_out;
    const int nbk = (N + RPB - 1) / RPB;  // 1563

    char* ws = (char*)d_ws;
    size_t off = 0;
    auto carve = [&](size_t bytes) {
        void* p = ws + off;
        off = (off + bytes + 255) & ~(size_t)255;
        return p;
    };
    half_t* xh = (half_t*)carve((size_t)N * DIMS * sizeof(half_t));  // also layer-2 output
    half_t* embB1 = (half_t*)carve((size_t)N * DIMS * sizeof(half_t));
    half_t* acc_h = (half_t*)carve((size_t)N * DIMS * sizeof(half_t));
    int2* staged = (int2*)carve((size_t)nbk * CAP * sizeof(int2));
    int* rowinfo = (int*)carve((size_t)N * sizeof(int));
    // hist (6.4 MB) aliases embB1 (25.6 MB): hist is dead before spmm<0> writes embB1
    int* hist = (int*)embB1;
    (void)ws_size;

    hipMemsetAsync(hist, 0, (size_t)nbk * NBINS * sizeof(int), stream);
    const int n2 = N * DIMS / 2;
    cvt_kernel<<<(n2 + 255) / 256, 256, 0, stream>>>(x, xh, n2);
    const int eblocks = (E + 1023) / 1024;
    hist_kernel<<<eblocks, 256, 0, stream>>>(erow, ecol, E, hist);
    scan_kernel<<<nbk, 256, 0, stream>>>(hist, rowinfo, N);
    scatter_kernel<<<eblocks, 256, 0, stream>>>(erow, ecol, eval, E, hist, staged);

    const int spmm_blocks = (N + 3) / 4;  // 4 waves (rows) per 256-thread block
    spmm_kernel<0><<<spmm_blocks, 256, 0, stream>>>(xh, rowinfo, staged, N, embB1, acc_h, out);
    spmm_kernel<1><<<spmm_blocks, 256, 0, stream>>>(embB1, rowinfo, staged, N, xh, acc_h, out);
    spmm_kernel<2><<<spmm_blocks, 256, 0, stream>>>(xh, rowinfo, staged, N, embB1, acc_h, out);
}

// Round 3
// 546.712 us; speedup vs baseline: 3.2247x; 1.5104x over previous
//
#include <hip/hip_runtime.h>

#define DIMS 128
#define RPB 64           // rows per bucket
#define CAP 3072         // edge capacity per bucket (avg 2047, ~23 sigma margin)
#define NBK_MAX 1600
#define NBINS 1024       // 64 rows x 16 column bands (col band = col>>13 in [0,12])

typedef _Float16 half_t;
typedef _Float16 half2_t __attribute__((ext_vector_type(2)));

static __device__ __forceinline__ unsigned halfbits(float v) {
    half_t h = (half_t)v;
    unsigned short us;
    __builtin_memcpy(&us, &h, 2);
    return (unsigned)us;
}
static __device__ __forceinline__ half2_t h2(int b) { return __builtin_bit_cast(half2_t, b); }
static __device__ __forceinline__ int ih(half2_t h) { return __builtin_bit_cast(int, h); }

// fp32 -> fp16 convert (x -> xh), 2 elems/thread
__global__ void cvt_kernel(const float* __restrict__ src, half_t* __restrict__ dst, int n2) {
    int i = blockIdx.x * blockDim.x + threadIdx.x;
    if (i >= n2) return;
    float2 v = reinterpret_cast<const float2*>(src)[i];
    half2_t h;
    h.x = (half_t)v.x;
    h.y = (half_t)v.y;
    reinterpret_cast<half2_t*>(&dst[0])[i] = h;
}

// Binning pass: append (rl<<26 | col<<8, half2{v,v}) to bucket row>>6.
// col<<8 IS the byte offset into the fp16 table (col*128*2).
// Block-local LDS counts + one global range reservation per (block,bucket):
// writes land in contiguous per-bucket ranges (good line utilization), and
// the only global atomic is one per touched bucket per block.
__global__ __launch_bounds__(256) void binA_kernel(
    const int* __restrict__ row, const int* __restrict__ col,
    const float* __restrict__ val, int E, int nbk,
    int* __restrict__ fill, int2* __restrict__ staged) {
    __shared__ int cnt[NBK_MAX];
    __shared__ int base[NBK_MAX];
    const int t = threadIdx.x;
    const int tile0 = blockIdx.x * 8192;
    for (int j = t; j < nbk; j += 256) cnt[j] = 0;
    __syncthreads();
    for (int k = 0; k < 8; ++k) {
        int e = tile0 + (k * 256 + t) * 4;
        if (e + 3 < E) {
            int4 r4 = *reinterpret_cast<const int4*>(&row[e]);
            atomicAdd(&cnt[r4.x >> 6], 1);
            atomicAdd(&cnt[r4.y >> 6], 1);
            atomicAdd(&cnt[r4.z >> 6], 1);
            atomicAdd(&cnt[r4.w >> 6], 1);
        } else {
            for (int j = e; j < E; ++j) atomicAdd(&cnt[row[j] >> 6], 1);
        }
    }
    __syncthreads();
    for (int j = t; j < nbk; j += 256) {
        int c = cnt[j];
        base[j] = c ? atomicAdd(&fill[j], c) : 0;
        cnt[j] = 0;
    }
    __syncthreads();
    for (int k = 0; k < 8; ++k) {
        int e = tile0 + (k * 256 + t) * 4;
        int n = (e + 3 < E) ? 4 : max(0, E - e);
        if (n == 4) {
            int4 r4 = *reinterpret_cast<const int4*>(&row[e]);
            int4 c4 = *reinterpret_cast<const int4*>(&col[e]);
            float4 v4 = *reinterpret_cast<const float4*>(&val[e]);
            int rr[4] = {r4.x, r4.y, r4.z, r4.w};
            int cc[4] = {c4.x, c4.y, c4.z, c4.w};
            float vv[4] = {v4.x, v4.y, v4.z, v4.w};
#pragma unroll
            for (int j = 0; j < 4; ++j) {
                int b = rr[j] >> 6;
                int p = base[b] + atomicAdd(&cnt[b], 1);
                if (p < CAP) {
                    unsigned hb = halfbits(vv[j]);
                    int2 pk;
                    pk.x = (int)(((unsigned)(rr[j] & 63) << 26) | ((unsigned)cc[j] << 8));
                    pk.y = (int)((hb << 16) | hb);
                    staged[(size_t)b * CAP + p] = pk;
                }
            }
        } else {
            for (int j = e; j < e + n; ++j) {
                int r = row[j];
                int b = r >> 6;
                int p = base[b] + atomicAdd(&cnt[b], 1);
                if (p < CAP) {
                    unsigned hb = halfbits(val[j]);
                    int2 pk;
                    pk.x = (int)(((unsigned)(r & 63) << 26) | ((unsigned)col[j] << 8));
                    pk.y = (int)((hb << 16) | hb);
                    staged[(size_t)b * CAP + p] = pk;
                }
            }
        }
    }
}

// In-LDS counting sort of one bucket by (row_local, col band): key =
// (rl<<4)|band. Emits per-row (start<<16 | end) relative to bucket base.
__global__ __launch_bounds__(512) void sort_bucket(
    const int* __restrict__ fill, int2* __restrict__ staged,
    int* __restrict__ rowinfo, int N) {
    __shared__ int2 buf[CAP];    // 24 KB
    __shared__ int2 outb[CAP];   // 24 KB
    __shared__ int cur[NBINS];   // 4 KB
    __shared__ int wsum[8];
    const int b = blockIdx.x;
    const int t = threadIdx.x;
    const int w = t >> 6, lane = t & 63;
    const int cnt = min(fill[b], CAP);
    int2* gb = staged + (size_t)b * CAP;

    cur[2 * t] = 0;
    cur[2 * t + 1] = 0;
    for (int i = t; i < cnt; i += 512) buf[i] = gb[i];
    __syncthreads();
    for (int i = t; i < cnt; i += 512) {
        unsigned k = (unsigned)buf[i].x;
        int key = (int)((k >> 26) << 4) | (int)((k >> 21) & 0xF);
        atomicAdd(&cur[key], 1);
    }
    __syncthreads();
    int h0 = cur[2 * t], h1 = cur[2 * t + 1];
    int s = h0 + h1;
    int v = s;
    for (int d = 1; d < 64; d <<= 1) {
        int u = __shfl_up(v, d, 64);
        if (lane >= d) v += u;
    }
    if (lane == 63) wsum[w] = v;
    __syncthreads();
    if (t < 8) {
        int ws = wsum[t];
        int vv = ws;
        for (int d = 1; d < 8; d <<= 1) {
            int u = __shfl_up(vv, d, 64);
            if (t >= d) vv += u;
        }
        wsum[t] = vv - ws;
    }
    __syncthreads();
    int excl = wsum[w] + (v - s);
    cur[2 * t] = excl;
    cur[2 * t + 1] = excl + h0;
    __syncthreads();
    if (t < RPB) {
        int start = cur[t * 16];
        int end = (t == RPB - 1) ? cnt : cur[t * 16 + 16];
        int r = b * RPB + t;
        if (r < N) rowinfo[r] = (start << 16) | end;
    }
    __syncthreads();
    for (int i = t; i < cnt; i += 512) {
        int2 pk = buf[i];
        unsigned k = (unsigned)pk.x;
        int key = (int)((k >> 26) << 4) | (int)((k >> 21) & 0xF);
        int p = atomicAdd(&cur[key], 1);
        outb[p] = pk;
    }
    __syncthreads();
    for (int i = t; i < cnt; i += 512) gb[i] = outb[i];
}

// ---------------- SpMM: one wave per row, 16-lane edge groups ----------------
// Edge list loaded ONCE per row, coalesced (lane i holds edge start+i), then
// broadcast per 4-edge group via one __shfl pair. Each 16-lane group owns one
// edge per step; each lane gathers 16B (8 dims) with global_load_dwordx4 ->
// 8 cache lines in flight per gather instruction (vs 2 with dword), and
// ~2.5x fewer issue slots per edge. Cross-group 4-way butterfly at the end.
// NOTE (rule #20): every access to acc[][] must be a compile-time index --
// the tail is ONE masked 16-edge iteration, never a runtime-indexed loop.
// MODE 0: emb_out = A*xh;   acc_h = xh + A*xh        (layer 1)
// MODE 1: emb_out = A*e1;   acc_h += A*e1            (layer 2, emb_out==xh reused)
// MODE 2: out = (acc_h + A*e2) * 0.25  (fp32 final)  (layer 3)
template <int MODE>
__global__ __launch_bounds__(256) void spmm_kernel(
    const half_t* __restrict__ emb_in, const int* __restrict__ rowinfo,
    const int2* __restrict__ staged, int N,
    half_t* __restrict__ emb_out, half_t* __restrict__ acc_h,
    float* __restrict__ out) {
    const int r = (blockIdx.x * blockDim.x + threadIdx.x) >> 6;  // wave id = row
    const int lane = threadIdx.x & 63;
    if (r >= N) return;
    const int info = rowinfo[r];
    const int start = info >> 16;
    const int end = info & 0xFFFF;
    const int2* eb = staged + (size_t)(r >> 6) * CAP;
    const char* tbl = reinterpret_cast<const char*>(emb_in);
    const int g = lane >> 4;                          // edge group 0..3
    const unsigned q16 = (unsigned)(lane & 15) << 4;  // byte offset of this lane's 8 dims

    half2_t acc[4][4];
#pragma unroll
    for (int u = 0; u < 4; ++u)
#pragma unroll
        for (int s = 0; s < 4; ++s) acc[u][s] = (half2_t)0;

    for (int base = start; base < end; base += 64) {
        const int cnt = min(64, end - base);
        int2 myE = make_int2(0, 0);
        if (base + lane < end) myE = eb[base + lane];

        int k = 0;
        for (; k + 16 <= cnt; k += 16) {
            int ex[4], ey[4];
#pragma unroll
            for (int u = 0; u < 4; ++u) {
                ex[u] = __shfl(myE.x, k + 4 * u + g, 64);
                ey[u] = __shfl(myE.y, k + 4 * u + g, 64);
            }
            int4 tv[4];
#pragma unroll
            for (int u = 0; u < 4; ++u) {
                unsigned voff = ((unsigned)ex[u] & 0x03FFFF00u) + q16;
                tv[u] = *reinterpret_cast<const int4*>(tbl + voff);
            }
#pragma unroll
            for (int u = 0; u < 4; ++u) {
                half2_t vv = h2(ey[u]);
                acc[u][0] = h2(tv[u].x) * vv + acc[u][0];
                acc[u][1] = h2(tv[u].y) * vv + acc[u][1];
                acc[u][2] = h2(tv[u].z) * vv + acc[u][2];
                acc[u][3] = h2(tv[u].w) * vv + acc[u][3];
            }
        }
        // tail (< 16 edges): one masked iteration, statically indexed.
        // Groups past cnt read a clamped (valid) edge but with val = 0.
        if (k < cnt) {
            int ex[4], ey[4];
#pragma unroll
            for (int u = 0; u < 4; ++u) {
                const int idx = k + 4 * u + g;
                const int cl = min(idx, cnt - 1);
                ex[u] = __shfl(myE.x, cl, 64);
                int tmp = __shfl(myE.y, cl, 64);
                ey[u] = (idx < cnt) ? tmp : 0;
            }
            int4 tv[4];
#pragma unroll
            for (int u = 0; u < 4; ++u) {
                unsigned voff = ((unsigned)ex[u] & 0x03FFFF00u) + q16;
                tv[u] = *reinterpret_cast<const int4*>(tbl + voff);
            }
#pragma unroll
            for (int u = 0; u < 4; ++u) {
                half2_t vv = h2(ey[u]);
                acc[u][0] = h2(tv[u].x) * vv + acc[u][0];
                acc[u][1] = h2(tv[u].y) * vv + acc[u][1];
                acc[u][2] = h2(tv[u].z) * vv + acc[u][2];
                acc[u][3] = h2(tv[u].w) * vv + acc[u][3];
            }
        }
    }

    half2_t a0 = (acc[0][0] + acc[1][0]) + (acc[2][0] + acc[3][0]);
    half2_t a1 = (acc[0][1] + acc[1][1]) + (acc[2][1] + acc[3][1]);
    half2_t a2 = (acc[0][2] + acc[1][2]) + (acc[2][2] + acc[3][2]);
    half2_t a3 = (acc[0][3] + acc[1][3]) + (acc[2][3] + acc[3][3]);
    // combine the 4 edge groups: lanes q, q+16, q+32, q+48 hold the same dims
#pragma unroll
    for (int off = 16; off < 64; off <<= 1) {
        a0 = a0 + h2(__shfl_xor(ih(a0), off, 64));
        a1 = a1 + h2(__shfl_xor(ih(a1), off, 64));
        a2 = a2 + h2(__shfl_xor(ih(a2), off, 64));
        a3 = a3 + h2(__shfl_xor(ih(a3), off, 64));
    }

    if (lane < 16) {
        const size_t o = (size_t)r * DIMS + ((size_t)lane << 3);  // 8 halves / lane
        if (MODE == 0 || MODE == 1) {
            *reinterpret_cast<int4*>(&emb_out[o]) = make_int4(ih(a0), ih(a1), ih(a2), ih(a3));
        }
        if (MODE == 0) {
            int4 xv = *reinterpret_cast<const int4*>(&emb_in[o]);
            *reinterpret_cast<int4*>(&acc_h[o]) = make_int4(
                ih(h2(xv.x) + a0), ih(h2(xv.y) + a1), ih(h2(xv.z) + a2), ih(h2(xv.w) + a3));
        } else if (MODE == 1) {
            int4 cv = *reinterpret_cast<const int4*>(&acc_h[o]);
            *reinterpret_cast<int4*>(&acc_h[o]) = make_int4(
                ih(h2(cv.x) + a0), ih(h2(cv.y) + a1), ih(h2(cv.z) + a2), ih(h2(cv.w) + a3));
        } else {
            int4 cv = *reinterpret_cast<const int4*>(&acc_h[o]);
            half2_t c0 = h2(cv.x), c1 = h2(cv.y), c2 = h2(cv.z), c3 = h2(cv.w);
            float4 f0 = make_float4(((float)c0.x + (float)a0.x) * 0.25f,
                                    ((float)c0.y + (float)a0.y) * 0.25f,
                                    ((float)c1.x + (float)a1.x) * 0.25f,
                                    ((float)c1.y + (float)a1.y) * 0.25f);
            float4 f1 = make_float4(((float)c2.x + (float)a2.x) * 0.25f,
                                    ((float)c2.y + (float)a2.y) * 0.25f,
                                    ((float)c3.x + (float)a3.x) * 0.25f,
                                    ((float)c3.y + (float)a3.y) * 0.25f);
            float4* po = reinterpret_cast<float4*>(&out[o]);
            po[0] = f0;
            po[1] = f1;
        }
    }
}

// ---------------- launch ----------------

extern "C" void kernel_launch(void* const* d_in, const int* in_sizes, int n_in,
                              void* d_out, int out_size, void* d_ws, size_t ws_size,
                              hipStream_t stream) {
    const float* x = (const float*)d_in[0];
    const int* erow = (const int*)d_in[1];
    const int* ecol = (const int*)d_in[2];
    const float* eval = (const float*)d_in[3];
    const int N = in_sizes[0] / DIMS;  // 100000
    const int E = in_sizes[1];         // 3200000
    float* out = (float*)d_out;
    const int nbk = (N + RPB - 1) / RPB;  // 1563

    char* ws = (char*)d_ws;
    size_t off = 0;
    auto carve = [&](size_t bytes) {
        void* p = ws + off;
        off = (off + bytes + 255) & ~(size_t)255;
        return p;
    };
    half_t* xh = (half_t*)carve((size_t)N * DIMS * sizeof(half_t));  // also layer-2 output
    half_t* embB1 = (half_t*)carve((size_t)N * DIMS * sizeof(half_t));
    half_t* acc_h = (half_t*)carve((size_t)N * DIMS * sizeof(half_t));
    int2* staged = (int2*)carve((size_t)nbk * CAP * sizeof(int2));
    int* fill = (int*)carve((size_t)nbk * sizeof(int));
    int* rowinfo = (int*)carve((size_t)N * sizeof(int));
    (void)ws_size;

    hipMemsetAsync(fill, 0, (size_t)nbk * sizeof(int), stream);
    const int n2 = N * DIMS / 2;
    cvt_kernel<<<(n2 + 255) / 256, 256, 0, stream>>>(x, xh, n2);
    binA_kernel<<<(E + 8191) / 8192, 256, 0, stream>>>(erow, ecol, eval, E, nbk, fill, staged);
    sort_bucket<<<nbk, 512, 0, stream>>>(fill, staged, rowinfo, N);

    const int spmm_blocks = (N + 3) / 4;  // 4 waves (rows) per 256-thread block
    spmm_kernel<0><<<spmm_blocks, 256, 0, stream>>>(xh, rowinfo, staged, N, embB1, acc_h, out);
    spmm_kernel<1><<<spmm_blocks, 256, 0, stream>>>(embB1, rowinfo, staged, N, xh, acc_h, out);
    spmm_kernel<2><<<spmm_blocks, 256, 0, stream>>>(xh, rowinfo, staged, N, embB1, acc_h, out);
}

// Round 4
// 538.023 us; speedup vs baseline: 3.2768x; 1.0161x over previous
//
#include <hip/hip_runtime.h>

#define DIMS 128
#define RPB 64           // rows per bucket
#define CAP 3072         // edge capacity per bucket (avg 2047, ~23 sigma margin)
#define NBK_MAX 1600
#define NBINS 1024       // 64 rows x 16 column bands (col band = col>>13 in [0,12])

typedef _Float16 half_t;
typedef _Float16 half2_t __attribute__((ext_vector_type(2)));

static __device__ __forceinline__ unsigned halfbits(float v) {
    half_t h = (half_t)v;
    unsigned short us;
    __builtin_memcpy(&us, &h, 2);
    return (unsigned)us;
}
static __device__ __forceinline__ half2_t h2(int b) { return __builtin_bit_cast(half2_t, b); }
static __device__ __forceinline__ int ih(half2_t h) { return __builtin_bit_cast(int, h); }

// fp32 -> fp16 convert (x -> xh), 2 elems/thread
__global__ void cvt_kernel(const float* __restrict__ src, half_t* __restrict__ dst, int n2) {
    int i = blockIdx.x * blockDim.x + threadIdx.x;
    if (i >= n2) return;
    float2 v = reinterpret_cast<const float2*>(src)[i];
    half2_t h;
    h.x = (half_t)v.x;
    h.y = (half_t)v.y;
    reinterpret_cast<half2_t*>(&dst[0])[i] = h;
}

// Binning pass: append (rl<<26 | col<<8, half2{v,v}) to bucket row>>6.
// col<<8 IS the byte offset into the fp16 table (col*128*2).
// 512 threads/block (12 waves/CU at 391 blocks) to hide the LDS-atomic chain
// + scattered-store latency; per-(block,bucket) run length stays 5.2 edges
// (8192-edge tile), preserving write coalescing.
__global__ __launch_bounds__(512) void binA_kernel(
    const int* __restrict__ row, const int* __restrict__ col,
    const float* __restrict__ val, int E, int nbk,
    int* __restrict__ fill, int2* __restrict__ staged) {
    __shared__ int cnt[NBK_MAX];
    __shared__ int base[NBK_MAX];
    const int t = threadIdx.x;
    const int tile0 = blockIdx.x * 8192;
    for (int j = t; j < nbk; j += 512) cnt[j] = 0;
    __syncthreads();
    for (int k = 0; k < 4; ++k) {
        int e = tile0 + (k * 512 + t) * 4;
        if (e + 3 < E) {
            int4 r4 = *reinterpret_cast<const int4*>(&row[e]);
            atomicAdd(&cnt[r4.x >> 6], 1);
            atomicAdd(&cnt[r4.y >> 6], 1);
            atomicAdd(&cnt[r4.z >> 6], 1);
            atomicAdd(&cnt[r4.w >> 6], 1);
        } else {
            for (int j = e; j < E; ++j) atomicAdd(&cnt[row[j] >> 6], 1);
        }
    }
    __syncthreads();
    for (int j = t; j < nbk; j += 512) {
        int c = cnt[j];
        base[j] = c ? atomicAdd(&fill[j], c) : 0;
        cnt[j] = 0;
    }
    __syncthreads();
    for (int k = 0; k < 4; ++k) {
        int e = tile0 + (k * 512 + t) * 4;
        int n = (e + 3 < E) ? 4 : max(0, E - e);
        if (n == 4) {
            int4 r4 = *reinterpret_cast<const int4*>(&row[e]);
            int4 c4 = *reinterpret_cast<const int4*>(&col[e]);
            float4 v4 = *reinterpret_cast<const float4*>(&val[e]);
            int rr[4] = {r4.x, r4.y, r4.z, r4.w};
            int cc[4] = {c4.x, c4.y, c4.z, c4.w};
            float vv[4] = {v4.x, v4.y, v4.z, v4.w};
#pragma unroll
            for (int j = 0; j < 4; ++j) {
                int b = rr[j] >> 6;
                int p = base[b] + atomicAdd(&cnt[b], 1);
                if (p < CAP) {
                    unsigned hb = halfbits(vv[j]);
                    int2 pk;
                    pk.x = (int)(((unsigned)(rr[j] & 63) << 26) | ((unsigned)cc[j] << 8));
                    pk.y = (int)((hb << 16) | hb);
                    staged[(size_t)b * CAP + p] = pk;
                }
            }
        } else {
            for (int j = e; j < e + n; ++j) {
                int r = row[j];
                int b = r >> 6;
                int p = base[b] + atomicAdd(&cnt[b], 1);
                if (p < CAP) {
                    unsigned hb = halfbits(val[j]);
                    int2 pk;
                    pk.x = (int)(((unsigned)(r & 63) << 26) | ((unsigned)col[j] << 8));
                    pk.y = (int)((hb << 16) | hb);
                    staged[(size_t)b * CAP + p] = pk;
                }
            }
        }
    }
}

// In-LDS counting sort of one bucket by (row_local, col band): key =
// (rl<<4)|band. Emits per-row (start<<16 | end) relative to bucket base.
// No input-side LDS buffer: the bucket's 16 KB stays L2-hot between the
// histogram and scatter passes, so LDS = outb+cur = 28 KB -> 4 blocks/CU
// (32 waves, the wave cap) instead of 3.
__global__ __launch_bounds__(512) void sort_bucket(
    const int* __restrict__ fill, int2* __restrict__ staged,
    int* __restrict__ rowinfo, int N) {
    __shared__ int2 outb[CAP];   // 24 KB
    __shared__ int cur[NBINS];   // 4 KB
    __shared__ int wsum[8];
    const int b = blockIdx.x;
    const int t = threadIdx.x;
    const int w = t >> 6, lane = t & 63;
    const int cnt = min(fill[b], CAP);
    int2* gb = staged + (size_t)b * CAP;

    cur[2 * t] = 0;
    cur[2 * t + 1] = 0;
    __syncthreads();
    for (int i = t; i < cnt; i += 512) {
        unsigned k = (unsigned)gb[i].x;
        int key = (int)((k >> 26) << 4) | (int)((k >> 21) & 0xF);
        atomicAdd(&cur[key], 1);
    }
    __syncthreads();
    int h0 = cur[2 * t], h1 = cur[2 * t + 1];
    int s = h0 + h1;
    int v = s;
    for (int d = 1; d < 64; d <<= 1) {
        int u = __shfl_up(v, d, 64);
        if (lane >= d) v += u;
    }
    if (lane == 63) wsum[w] = v;
    __syncthreads();
    if (t < 8) {
        int ws = wsum[t];
        int vv = ws;
        for (int d = 1; d < 8; d <<= 1) {
            int u = __shfl_up(vv, d, 64);
            if (t >= d) vv += u;
        }
        wsum[t] = vv - ws;
    }
    __syncthreads();
    int excl = wsum[w] + (v - s);
    cur[2 * t] = excl;
    cur[2 * t + 1] = excl + h0;
    __syncthreads();
    if (t < RPB) {
        int start = cur[t * 16];
        int end = (t == RPB - 1) ? cnt : cur[t * 16 + 16];
        int r = b * RPB + t;
        if (r < N) rowinfo[r] = (start << 16) | end;
    }
    __syncthreads();
    for (int i = t; i < cnt; i += 512) {
        int2 pk = gb[i];
        unsigned k = (unsigned)pk.x;
        int key = (int)((k >> 26) << 4) | (int)((k >> 21) & 0xF);
        int p = atomicAdd(&cur[key], 1);
        outb[p] = pk;
    }
    __syncthreads();
    for (int i = t; i < cnt; i += 512) gb[i] = outb[i];
}

// ---------------- SpMM: one wave per row, 16-lane edge groups ----------------
// (unchanged from round 3 -- confirmed memory-system-bound at ~113 us; see
// round-3 post-mortem. Issue-rate cuts are null.)
// MODE 0: emb_out = A*xh;   acc_h = xh + A*xh        (layer 1)
// MODE 1: emb_out = A*e1;   acc_h += A*e1            (layer 2, emb_out==xh reused)
// MODE 2: out = (acc_h + A*e2) * 0.25  (fp32 final)  (layer 3)
template <int MODE>
__global__ __launch_bounds__(256) void spmm_kernel(
    const half_t* __restrict__ emb_in, const int* __restrict__ rowinfo,
    const int2* __restrict__ staged, int N,
    half_t* __restrict__ emb_out, half_t* __restrict__ acc_h,
    float* __restrict__ out) {
    const int r = (blockIdx.x * blockDim.x + threadIdx.x) >> 6;  // wave id = row
    const int lane = threadIdx.x & 63;
    if (r >= N) return;
    const int info = rowinfo[r];
    const int start = info >> 16;
    const int end = info & 0xFFFF;
    const int2* eb = staged + (size_t)(r >> 6) * CAP;
    const char* tbl = reinterpret_cast<const char*>(emb_in);
    const int g = lane >> 4;                          // edge group 0..3
    const unsigned q16 = (unsigned)(lane & 15) << 4;  // byte offset of this lane's 8 dims

    half2_t acc[4][4];
#pragma unroll
    for (int u = 0; u < 4; ++u)
#pragma unroll
        for (int s = 0; s < 4; ++s) acc[u][s] = (half2_t)0;

    for (int base = start; base < end; base += 64) {
        const int cnt = min(64, end - base);
        int2 myE = make_int2(0, 0);
        if (base + lane < end) myE = eb[base + lane];

        int k = 0;
        for (; k + 16 <= cnt; k += 16) {
            int ex[4], ey[4];
#pragma unroll
            for (int u = 0; u < 4; ++u) {
                ex[u] = __shfl(myE.x, k + 4 * u + g, 64);
                ey[u] = __shfl(myE.y, k + 4 * u + g, 64);
            }
            int4 tv[4];
#pragma unroll
            for (int u = 0; u < 4; ++u) {
                unsigned voff = ((unsigned)ex[u] & 0x03FFFF00u) + q16;
                tv[u] = *reinterpret_cast<const int4*>(tbl + voff);
            }
#pragma unroll
            for (int u = 0; u < 4; ++u) {
                half2_t vv = h2(ey[u]);
                acc[u][0] = h2(tv[u].x) * vv + acc[u][0];
                acc[u][1] = h2(tv[u].y) * vv + acc[u][1];
                acc[u][2] = h2(tv[u].z) * vv + acc[u][2];
                acc[u][3] = h2(tv[u].w) * vv + acc[u][3];
            }
        }
        // tail (< 16 edges): one masked iteration, statically indexed.
        // Groups past cnt read a clamped (valid) edge but with val = 0.
        if (k < cnt) {
            int ex[4], ey[4];
#pragma unroll
            for (int u = 0; u < 4; ++u) {
                const int idx = k + 4 * u + g;
                const int cl = min(idx, cnt - 1);
                ex[u] = __shfl(myE.x, cl, 64);
                int tmp = __shfl(myE.y, cl, 64);
                ey[u] = (idx < cnt) ? tmp : 0;
            }
            int4 tv[4];
#pragma unroll
            for (int u = 0; u < 4; ++u) {
                unsigned voff = ((unsigned)ex[u] & 0x03FFFF00u) + q16;
                tv[u] = *reinterpret_cast<const int4*>(tbl + voff);
            }
#pragma unroll
            for (int u = 0; u < 4; ++u) {
                half2_t vv = h2(ey[u]);
                acc[u][0] = h2(tv[u].x) * vv + acc[u][0];
                acc[u][1] = h2(tv[u].y) * vv + acc[u][1];
                acc[u][2] = h2(tv[u].z) * vv + acc[u][2];
                acc[u][3] = h2(tv[u].w) * vv + acc[u][3];
            }
        }
    }

    half2_t a0 = (acc[0][0] + acc[1][0]) + (acc[2][0] + acc[3][0]);
    half2_t a1 = (acc[0][1] + acc[1][1]) + (acc[2][1] + acc[3][1]);
    half2_t a2 = (acc[0][2] + acc[1][2]) + (acc[2][2] + acc[3][2]);
    half2_t a3 = (acc[0][3] + acc[1][3]) + (acc[2][3] + acc[3][3]);
    // combine the 4 edge groups: lanes q, q+16, q+32, q+48 hold the same dims
#pragma unroll
    for (int off = 16; off < 64; off <<= 1) {
        a0 = a0 + h2(__shfl_xor(ih(a0), off, 64));
        a1 = a1 + h2(__shfl_xor(ih(a1), off, 64));
        a2 = a2 + h2(__shfl_xor(ih(a2), off, 64));
        a3 = a3 + h2(__shfl_xor(ih(a3), off, 64));
    }

    if (lane < 16) {
        const size_t o = (size_t)r * DIMS + ((size_t)lane << 3);  // 8 halves / lane
        if (MODE == 0 || MODE == 1) {
            *reinterpret_cast<int4*>(&emb_out[o]) = make_int4(ih(a0), ih(a1), ih(a2), ih(a3));
        }
        if (MODE == 0) {
            int4 xv = *reinterpret_cast<const int4*>(&emb_in[o]);
            *reinterpret_cast<int4*>(&acc_h[o]) = make_int4(
                ih(h2(xv.x) + a0), ih(h2(xv.y) + a1), ih(h2(xv.z) + a2), ih(h2(xv.w) + a3));
        } else if (MODE == 1) {
            int4 cv = *reinterpret_cast<const int4*>(&acc_h[o]);
            *reinterpret_cast<int4*>(&acc_h[o]) = make_int4(
                ih(h2(cv.x) + a0), ih(h2(cv.y) + a1), ih(h2(cv.z) + a2), ih(h2(cv.w) + a3));
        } else {
            int4 cv = *reinterpret_cast<const int4*>(&acc_h[o]);
            half2_t c0 = h2(cv.x), c1 = h2(cv.y), c2 = h2(cv.z), c3 = h2(cv.w);
            float4 f0 = make_float4(((float)c0.x + (float)a0.x) * 0.25f,
                                    ((float)c0.y + (float)a0.y) * 0.25f,
                                    ((float)c1.x + (float)a1.x) * 0.25f,
                                    ((float)c1.y + (float)a1.y) * 0.25f);
            float4 f1 = make_float4(((float)c2.x + (float)a2.x) * 0.25f,
                                    ((float)c2.y + (float)a2.y) * 0.25f,
                                    ((float)c3.x + (float)a3.x) * 0.25f,
                                    ((float)c3.y + (float)a3.y) * 0.25f);
            float4* po = reinterpret_cast<float4*>(&out[o]);
            po[0] = f0;
            po[1] = f1;
        }
    }
}

// ---------------- launch ----------------

extern "C" void kernel_launch(void* const* d_in, const int* in_sizes, int n_in,
                              void* d_out, int out_size, void* d_ws, size_t ws_size,
                              hipStream_t stream) {
    const float* x = (const float*)d_in[0];
    const int* erow = (const int*)d_in[1];
    const int* ecol = (const int*)d_in[2];
    const float* eval = (const float*)d_in[3];
    const int N = in_sizes[0] / DIMS;  // 100000
    const int E = in_sizes[1];         // 3200000
    float* out = (float*)d_out;
    const int nbk = (N + RPB - 1) / RPB;  // 1563

    char* ws = (char*)d_ws;
    size_t off = 0;
    auto carve = [&](size_t bytes) {
        void* p = ws + off;
        off = (off + bytes + 255) & ~(size_t)255;
        return p;
    };
    half_t* xh = (half_t*)carve((size_t)N * DIMS * sizeof(half_t));  // also layer-2 output
    half_t* embB1 = (half_t*)carve((size_t)N * DIMS * sizeof(half_t));
    half_t* acc_h = (half_t*)carve((size_t)N * DIMS * sizeof(half_t));
    int2* staged = (int2*)carve((size_t)nbk * CAP * sizeof(int2));
    int* fill = (int*)carve((size_t)nbk * sizeof(int));
    int* rowinfo = (int*)carve((size_t)N * sizeof(int));
    (void)ws_size;

    hipMemsetAsync(fill, 0, (size_t)nbk * sizeof(int), stream);
    const int n2 = N * DIMS / 2;
    cvt_kernel<<<(n2 + 255) / 256, 256, 0, stream>>>(x, xh, n2);
    binA_kernel<<<(E + 8191) / 8192, 512, 0, stream>>>(erow, ecol, eval, E, nbk, fill, staged);
    sort_bucket<<<nbk, 512, 0, stream>>>(fill, staged, rowinfo, N);

    const int spmm_blocks = (N + 3) / 4;  // 4 waves (rows) per 256-thread block
    spmm_kernel<0><<<spmm_blocks, 256, 0, stream>>>(xh, rowinfo, staged, N, embB1, acc_h, out);
    spmm_kernel<1><<<spmm_blocks, 256, 0, stream>>>(embB1, rowinfo, staged, N, xh, acc_h, out);
    spmm_kernel<2><<<spmm_blocks, 256, 0, stream>>>(xh, rowinfo, staged, N, embB1, acc_h, out);
}